// Round 7
// baseline (419.867 us; speedup 1.0000x reference)
//
#include <hip/hip_runtime.h>
#include <stdint.h>

#define EPS_BN 1e-5f

typedef __attribute__((ext_vector_type(8))) short short8v;   // 8 bf16 = 4 VGPR
typedef __attribute__((ext_vector_type(4))) float f32x4;     // MFMA accumulator

__device__ __forceinline__ unsigned rne_bf16(float f) {      // round-to-nearest-even
    unsigned u = __float_as_uint(f);
    return (u + 0x7FFFu + ((u >> 16) & 1u)) >> 16;
}

// ============================================================================
// prep: fp32 -> bf16 feature conversion, weight transpose+concat to bf16
// ============================================================================
extern "C" __global__ __launch_bounds__(256)
void f32_to_bf16_kernel(const float4* __restrict__ in, uint2* __restrict__ out, long n4) {
    long i = (long)blockIdx.x * 256 + threadIdx.x;
    long stride = (long)gridDim.x * 256;
    for (; i < n4; i += stride) {
        float4 v = in[i];
        uint2 o;
        o.x = rne_bf16(v.x) | (rne_bf16(v.y) << 16);
        o.y = rne_bf16(v.z) | (rne_bf16(v.w) << 16);
        out[i] = o;
    }
}

// Wt[col][k] for both layers in one launch: blocks 0-127 -> Wt0, 128-255 -> Wt1
extern "C" __global__ __launch_bounds__(256)
void wt_prep2_kernel(const float* __restrict__ Wl0, const float* __restrict__ Wr0,
                     unsigned short* __restrict__ Wt0,
                     const float* __restrict__ Wl1, const float* __restrict__ Wr1,
                     unsigned short* __restrict__ Wt1) {
    int b = blockIdx.x;
    const float* Wl = (b < 128) ? Wl0 : Wl1;
    const float* Wr = (b < 128) ? Wr0 : Wr1;
    unsigned short* Wt = (b < 128) ? Wt0 : Wt1;
    int idx = (b & 127) * 256 + threadIdx.x;       // 128*256 = 32768 per layer
    int col = idx >> 8, k = idx & 255;
    float v = (k < 128) ? Wl[(size_t)k * 128 + col] : Wr[(size_t)(k - 128) * 128 + col];
    Wt[(size_t)col * 256 + k] = (unsigned short)rne_bf16(v);
}

// ============================================================================
// 4-way linked lists (once; shared by both layers)
//   head4[node*4+c] -> most recent edge with e&3==c; pair[e] = (src, prev)
// ============================================================================
extern "C" __global__ __launch_bounds__(256)
void init_head_kernel(int* __restrict__ head, int n) {
    int i = blockIdx.x * 256 + threadIdx.x;
    if (i < n) head[i] = -1;
}

extern "C" __global__ __launch_bounds__(256)
void link_kernel(const int* __restrict__ ei, int* __restrict__ head4,
                 uint2* __restrict__ pair, int E) {
    int e = blockIdx.x * 256 + threadIdx.x;
    if (e < E) {
        int src = ei[e];
        int dst = ei[E + e];
        int old = atomicExch(&head4[dst * 4 + (e & 3)], e);
        uint2 p; p.x = (unsigned)src; p.y = (unsigned)old;
        pair[e] = p;                 // coalesced 8B write
    }
}

// ============================================================================
// gather-max over bf16 rows: 16 lanes/node, uint4 (8 bf16) per lane,
// 4 independent chase chains per node (4x MLP on the dependent loads).
// fmax trick: hi bf16 compared as raw u32-as-float (low-16 garbage is sub-ulp).
// accumulators start at -inf; empty node writes 0 (PyG empty-segment fill).
// Also zeroes stats[0..255] from block 0.
// ============================================================================
#define FM8(v)                                              \
    a0 = fmaxf(a0, __uint_as_float((v).x << 16));           \
    a1 = fmaxf(a1, __uint_as_float((v).x));                 \
    a2 = fmaxf(a2, __uint_as_float((v).y << 16));           \
    a3 = fmaxf(a3, __uint_as_float((v).y));                 \
    a4 = fmaxf(a4, __uint_as_float((v).z << 16));           \
    a5 = fmaxf(a5, __uint_as_float((v).z));                 \
    a6 = fmaxf(a6, __uint_as_float((v).w << 16));           \
    a7 = fmaxf(a7, __uint_as_float((v).w));

extern "C" __global__ __launch_bounds__(256, 8)
void gather_max_ll16_kernel(const uint4* __restrict__ x16r, const int* __restrict__ head4,
                            const uint2* __restrict__ pair,
                            uint4* __restrict__ agg16, float* __restrict__ stats, int Nn) {
    if (blockIdx.x == 0 && threadIdx.x < 256) stats[threadIdx.x] = 0.0f;
    int t = blockIdx.x * 256 + threadIdx.x;
    int node = t >> 4;
    if (node >= Nn) return;
    int lane = t & 15;

    int4 hh = *(const int4*)(head4 + (size_t)node * 4);
    int e0 = hh.x, e1 = hh.y, e2 = hh.z, e3 = hh.w;

    uint4 out;
    if ((e0 & e1 & e2 & e3) < 0 && e0 < 0 && e1 < 0 && e2 < 0 && e3 < 0) {
        out.x = out.y = out.z = out.w = 0u;
    } else {
        float a0 = -INFINITY, a1 = -INFINITY, a2 = -INFINITY, a3 = -INFINITY;
        float a4 = -INFINITY, a5 = -INFINITY, a6 = -INFINITY, a7 = -INFINITY;
        while ((e0 & e1 & e2 & e3) >= 0 || e0 >= 0 || e1 >= 0 || e2 >= 0 || e3 >= 0) {
            bool b0 = e0 >= 0, b1 = e1 >= 0, b2 = e2 >= 0, b3 = e3 >= 0;
            uint2 p0, p1, p2, p3;
            uint4 v0, v1, v2, v3;
            if (b0) p0 = pair[e0];
            if (b1) p1 = pair[e1];
            if (b2) p2 = pair[e2];
            if (b3) p3 = pair[e3];
            if (b0) v0 = x16r[(size_t)p0.x * 16 + lane];
            if (b1) v1 = x16r[(size_t)p1.x * 16 + lane];
            if (b2) v2 = x16r[(size_t)p2.x * 16 + lane];
            if (b3) v3 = x16r[(size_t)p3.x * 16 + lane];
            if (b0) { e0 = (int)p0.y; FM8(v0); }
            if (b1) { e1 = (int)p1.y; FM8(v1); }
            if (b2) { e2 = (int)p2.y; FM8(v2); }
            if (b3) { e3 = (int)p3.y; FM8(v3); }
        }
        out.x = (__float_as_uint(a0) >> 16) | (__float_as_uint(a1) & 0xFFFF0000u);
        out.y = (__float_as_uint(a2) >> 16) | (__float_as_uint(a3) & 0xFFFF0000u);
        out.z = (__float_as_uint(a4) >> 16) | (__float_as_uint(a5) & 0xFFFF0000u);
        out.w = (__float_as_uint(a6) >> 16) | (__float_as_uint(a7) & 0xFFFF0000u);
    }
    agg16[(size_t)node * 16 + lane] = out;
}

// ============================================================================
// MFMA GEMM: h = [agg16 | xin16] @ Wt^T + bias, fused BN col-stats
// 256 thr = 4 waves (2x2), BM=128, BN=128, per wave 64x64 (4x4 frags 16x16),
// K=256 in 8 steps of 32. A/B fragments loaded straight from global (16B).
// ============================================================================
extern "C" __global__ __launch_bounds__(256)
void gemm_bf16_kernel(const unsigned short* __restrict__ agg16,
                      const unsigned short* __restrict__ xin16,
                      const unsigned short* __restrict__ Wt,
                      const float* __restrict__ bias,
                      float* __restrict__ h, float* __restrict__ stats, int nrows) {
    __shared__ float redS[4][128];
    __shared__ float redQ[4][128];

    const int t = threadIdx.x;
    const int w = t >> 6, l = t & 63;
    const int wm = w >> 1, wn = w & 1;
    const int r16 = l & 15, g = l >> 4;
    const int blockRow = blockIdx.x * 128;
    const int colBase = wn * 64;

    f32x4 acc[4][4];
#pragma unroll
    for (int m = 0; m < 4; ++m)
#pragma unroll
        for (int n = 0; n < 4; ++n) acc[m][n] = (f32x4){0.f, 0.f, 0.f, 0.f};

    const short8v az = {0, 0, 0, 0, 0, 0, 0, 0};

#pragma unroll
    for (int kt = 0; kt < 8; ++kt) {
        const unsigned short* Asrc = (kt < 4) ? agg16 : xin16;
        const int kofs = (kt < 4) ? kt * 32 : kt * 32 - 128;

        short8v b[4];
#pragma unroll
        for (int n = 0; n < 4; ++n) {
            int col = colBase + n * 16 + r16;
            b[n] = *(const short8v*)(Wt + (size_t)col * 256 + kt * 32 + g * 8);
        }
        short8v a[4];
#pragma unroll
        for (int m = 0; m < 4; ++m) {
            int row = blockRow + wm * 64 + m * 16 + r16;
            a[m] = (row < nrows)
                 ? *(const short8v*)(Asrc + (size_t)row * 128 + kofs + g * 8)
                 : az;
        }
#pragma unroll
        for (int m = 0; m < 4; ++m)
#pragma unroll
            for (int n = 0; n < 4; ++n)
                acc[m][n] = __builtin_amdgcn_mfma_f32_16x16x32_bf16(a[m], b[n], acc[m][n], 0, 0, 0);
    }

    // ---- epilogue: bias, store h, fused BN stats ----
    for (int i = t; i < 512; i += 256) {
        ((float*)redS)[i] = 0.f;
        ((float*)redQ)[i] = 0.f;
    }
    __syncthreads();

    float bcol[4];
#pragma unroll
    for (int n = 0; n < 4; ++n) bcol[n] = bias[colBase + n * 16 + r16];

    float s4[4] = {0.f, 0.f, 0.f, 0.f};
    float q4[4] = {0.f, 0.f, 0.f, 0.f};
#pragma unroll
    for (int m = 0; m < 4; ++m) {
#pragma unroll
        for (int reg = 0; reg < 4; ++reg) {
            int row = blockRow + wm * 64 + m * 16 + g * 4 + reg;   // C/D: row=(l>>4)*4+reg
            if (row < nrows) {
#pragma unroll
                for (int n = 0; n < 4; ++n) {
                    float o = acc[m][n][reg] + bcol[n];
                    h[(size_t)row * 128 + colBase + n * 16 + r16] = o;   // col=l&15
                    s4[n] += o;
                    q4[n] += o * o;
                }
            }
        }
    }
#pragma unroll
    for (int n = 0; n < 4; ++n) {     // reduce over the 4 k-groups (same col)
        s4[n] += __shfl_xor(s4[n], 16, 64);
        s4[n] += __shfl_xor(s4[n], 32, 64);
        q4[n] += __shfl_xor(q4[n], 16, 64);
        q4[n] += __shfl_xor(q4[n], 32, 64);
    }
    if (g == 0) {
#pragma unroll
        for (int n = 0; n < 4; ++n) {
            redS[w][colBase + n * 16 + r16] = s4[n];
            redQ[w][colBase + n * 16 + r16] = q4[n];
        }
    }
    __syncthreads();
    if (t < 128) {
        float s = redS[0][t] + redS[1][t] + redS[2][t] + redS[3][t];
        float q = redQ[0][t] + redQ[1][t] + redQ[2][t] + redQ[3][t];
        atomicAdd(&stats[t], s);
        atomicAdd(&stats[128 + t], q);
    }
}

// ============================================================================
// BatchNorm (finalize fused per block) + ReLU
// ============================================================================
__device__ __forceinline__ void bn_make_ss(const float* __restrict__ stats,
                                           const float* __restrict__ gamma,
                                           const float* __restrict__ beta,
                                           float inv_n, float* s_ss) {
    int t = threadIdx.x;
    if (t < 128) {
        float mu = stats[t] * inv_n;
        float var = stats[128 + t] * inv_n - mu * mu;
        float sc = gamma[t] * rsqrtf(var + EPS_BN);
        s_ss[t] = sc;
        s_ss[128 + t] = beta[t] - mu * sc;
    }
    __syncthreads();
}

// BN+ReLU -> bf16 (layer-1 intermediate for layer 2)
extern "C" __global__ __launch_bounds__(256)
void bn_relu_tobf16_kernel(const float4* __restrict__ h, const float* __restrict__ stats,
                           const float* __restrict__ gamma, const float* __restrict__ beta,
                           float inv_n, uint2* __restrict__ y16, long n4) {
    __shared__ float s_ss[256];
    bn_make_ss(stats, gamma, beta, inv_n, s_ss);
    long i = (long)blockIdx.x * blockDim.x + threadIdx.x;
    long stride = (long)gridDim.x * blockDim.x;
    for (; i < n4; i += stride) {
        int c4 = (int)(i & 31) * 4;
        float4 v = h[i];
        float o0 = fmaxf(fmaf(v.x, s_ss[c4 + 0], s_ss[128 + c4 + 0]), 0.f);
        float o1 = fmaxf(fmaf(v.y, s_ss[c4 + 1], s_ss[128 + c4 + 1]), 0.f);
        float o2 = fmaxf(fmaf(v.z, s_ss[c4 + 2], s_ss[128 + c4 + 2]), 0.f);
        float o3 = fmaxf(fmaf(v.w, s_ss[c4 + 3], s_ss[128 + c4 + 3]), 0.f);
        uint2 o;
        o.x = rne_bf16(o0) | (rne_bf16(o1) << 16);
        o.y = rne_bf16(o2) | (rne_bf16(o3) << 16);
        y16[i] = o;
    }
}

// BN+ReLU in place fp32 (final output)
extern "C" __global__ __launch_bounds__(256)
void bn_relu_f32_kernel(float4* __restrict__ h, const float* __restrict__ stats,
                        const float* __restrict__ gamma, const float* __restrict__ beta,
                        float inv_n, long n4) {
    __shared__ float s_ss[256];
    bn_make_ss(stats, gamma, beta, inv_n, s_ss);
    long i = (long)blockIdx.x * blockDim.x + threadIdx.x;
    long stride = (long)gridDim.x * blockDim.x;
    for (; i < n4; i += stride) {
        int c4 = (int)(i & 31) * 4;
        float4 v = h[i];
        v.x = fmaxf(fmaf(v.x, s_ss[c4 + 0], s_ss[128 + c4 + 0]), 0.f);
        v.y = fmaxf(fmaf(v.y, s_ss[c4 + 1], s_ss[128 + c4 + 1]), 0.f);
        v.z = fmaxf(fmaf(v.z, s_ss[c4 + 2], s_ss[128 + c4 + 2]), 0.f);
        v.w = fmaxf(fmaf(v.w, s_ss[c4 + 3], s_ss[128 + c4 + 3]), 0.f);
        h[i] = v;
    }
}

// ============================================================================
// fallback path (fp32 atomic scatter-max + VALU GEMM) — only if ws too small
// ============================================================================
__device__ __forceinline__ unsigned map_f(float f) {
    unsigned u = __float_as_uint(f);
    return (u & 0x80000000u) ? ~u : (u | 0x80000000u);
}
__device__ __forceinline__ float unmap_f(unsigned m) {
    return (m & 0x80000000u) ? __uint_as_float(m & 0x7FFFFFFFu) : __uint_as_float(~m);
}

extern "C" __global__ __launch_bounds__(256)
void init_sentinel_kernel(uint4* __restrict__ agg, long n4) {
    uint4 z = {0u, 0u, 0u, 0u};
    long i = (long)blockIdx.x * blockDim.x + threadIdx.x;
    long stride = (long)gridDim.x * blockDim.x;
    for (; i < n4; i += stride) agg[i] = z;
}

extern "C" __global__ __launch_bounds__(256)
void scatter_max_kernel(const float4* __restrict__ xin, const int* __restrict__ ei,
                        unsigned* __restrict__ agg, int E) {
    int t = blockIdx.x * 256 + threadIdx.x;
    int e = t >> 5;
    if (e >= E) return;
    int f4 = t & 31;
    int src = ei[e];
    int dst = ei[E + e];
    float4 v = xin[(size_t)src * 32 + f4];
    unsigned* p = agg + (size_t)dst * 128 + (size_t)f4 * 4;
    atomicMax(p + 0, map_f(v.x));
    atomicMax(p + 1, map_f(v.y));
    atomicMax(p + 2, map_f(v.z));
    atomicMax(p + 3, map_f(v.w));
}

extern "C" __global__ __launch_bounds__(256)
void unmap_kernel(unsigned* __restrict__ agg, long n) {
    long i = (long)blockIdx.x * blockDim.x + threadIdx.x;
    long stride = (long)gridDim.x * blockDim.x;
    for (; i < n; i += stride) {
        unsigned u = agg[i];
        agg[i] = __float_as_uint(u ? unmap_f(u) : 0.0f);
    }
}

extern "C" __global__
void zero_stats_kernel(float* __restrict__ stats) {
    stats[threadIdx.x] = 0.0f;
}

extern "C" __global__ __launch_bounds__(256)
void gemm_kernel(const float* __restrict__ agg, const float* __restrict__ xin,
                 const float* __restrict__ Wl, const float* __restrict__ Wr,
                 const float* __restrict__ bias, float* __restrict__ h,
                 float* __restrict__ stats, int nrows) {
    __shared__ __align__(16) float As[64][36];
    __shared__ __align__(16) float Bs[32][136];
    __shared__ float redS[4][128];
    __shared__ float redQ[4][128];

    const int t = threadIdx.x;
    const int tx = t & 15;
    const int ty = t >> 4;
    const int tx8 = tx * 8;
    const int ty4 = ty * 4;
    const int blockRow = blockIdx.x * 64;

    float acc[4][8];
#pragma unroll
    for (int j = 0; j < 4; ++j)
#pragma unroll
        for (int c = 0; c < 8; ++c) acc[j][c] = 0.0f;

    for (int kt = 0; kt < 8; ++kt) {
        const int k0 = kt * 32;
        const bool isAgg = (kt < 4);
        const float* W = isAgg ? Wl : Wr;
        const float* Asrc = isAgg ? agg : xin;
        const int kw = isAgg ? k0 : (k0 - 128);

#pragma unroll
        for (int it = 0; it < 4; ++it) {
            int idx = t + it * 256;
            int kr = idx >> 5, cq = idx & 31;
            float4 ww = *(const float4*)&W[(size_t)(kw + kr) * 128 + cq * 4];
            *(float4*)&Bs[kr][cq * 4] = ww;
        }
#pragma unroll
        for (int it = 0; it < 2; ++it) {
            int idx = t + it * 256;
            int r = idx >> 3, kq = idx & 7;
            int row_g = blockRow + r;
            float4 a = {0.f, 0.f, 0.f, 0.f};
            if (row_g < nrows)
                a = *(const float4*)&Asrc[(size_t)row_g * 128 + kw + kq * 4];
            *(float4*)&As[r][kq * 4] = a;
        }
        __syncthreads();

#pragma unroll
        for (int kk = 0; kk < 32; ++kk) {
            float aa[4];
            aa[0] = As[ty4 + 0][kk];
            aa[1] = As[ty4 + 1][kk];
            aa[2] = As[ty4 + 2][kk];
            aa[3] = As[ty4 + 3][kk];
            float4 b0 = *(const float4*)&Bs[kk][tx8];
            float4 b1 = *(const float4*)&Bs[kk][tx8 + 4];
            float bb[8] = {b0.x, b0.y, b0.z, b0.w, b1.x, b1.y, b1.z, b1.w};
#pragma unroll
            for (int j = 0; j < 4; ++j)
#pragma unroll
                for (int c = 0; c < 8; ++c)
                    acc[j][c] = fmaf(aa[j], bb[c], acc[j][c]);
        }
        __syncthreads();
    }

    float bv[8];
#pragma unroll
    for (int c = 0; c < 8; ++c) bv[c] = bias[tx8 + c];

    float s_loc[8], q_loc[8];
#pragma unroll
    for (int c = 0; c < 8; ++c) { s_loc[c] = 0.f; q_loc[c] = 0.f; }

#pragma unroll
    for (int j = 0; j < 4; ++j) {
        int row = blockRow + ty4 + j;
        if (row < nrows) {
            float o[8];
#pragma unroll
            for (int c = 0; c < 8; ++c) {
                o[c] = acc[j][c] + bv[c];
                s_loc[c] += o[c];
                q_loc[c] += o[c] * o[c];
            }
            float4 o0 = {o[0], o[1], o[2], o[3]};
            float4 o1 = {o[4], o[5], o[6], o[7]};
            *(float4*)&h[(size_t)row * 128 + tx8] = o0;
            *(float4*)&h[(size_t)row * 128 + tx8 + 4] = o1;
        }
    }

#pragma unroll
    for (int c = 0; c < 8; ++c) {
        s_loc[c] += __shfl_xor(s_loc[c], 16, 64);
        s_loc[c] += __shfl_xor(s_loc[c], 32, 64);
        q_loc[c] += __shfl_xor(q_loc[c], 16, 64);
        q_loc[c] += __shfl_xor(q_loc[c], 32, 64);
    }
    int wave = t >> 6;
    if ((t & 63) < 16) {
#pragma unroll
        for (int c = 0; c < 8; ++c) {
            redS[wave][tx8 + c] = s_loc[c];
            redQ[wave][tx8 + c] = q_loc[c];
        }
    }
    __syncthreads();
    if (t < 128) {
        float s = redS[0][t] + redS[1][t] + redS[2][t] + redS[3][t];
        float q = redQ[0][t] + redQ[1][t] + redQ[2][t] + redQ[3][t];
        atomicAdd(&stats[t], s);
        atomicAdd(&stats[128 + t], q);
    }
}

// ============================================================================
// host-side orchestration
// ============================================================================
static void run_layer_atomic(const float* in_feat, const int* ei, int Nn, int Ee,
                             const float* Wl, const float* bl, const float* Wr,
                             const float* gamma, const float* beta,
                             float* agg, float* stats, float* out, hipStream_t stream) {
    long aggN = (long)Nn * 128;
    long n4 = aggN / 4;

    zero_stats_kernel<<<1, 256, 0, stream>>>(stats);
    int initBlocks = (int)((n4 + 255) / 256);
    if (initBlocks > 4096) initBlocks = 4096;
    init_sentinel_kernel<<<initBlocks, 256, 0, stream>>>((uint4*)agg, n4);
    int sb = (int)(((long)Ee * 32 + 255) / 256);
    scatter_max_kernel<<<sb, 256, 0, stream>>>((const float4*)in_feat, ei,
                                               (unsigned*)agg, Ee);
    int ub = (int)((aggN + 255) / 256);
    if (ub > 8192) ub = 8192;
    unmap_kernel<<<ub, 256, 0, stream>>>((unsigned*)agg, aggN);
    gemm_kernel<<<(Nn + 63) / 64, 256, 0, stream>>>(agg, in_feat, Wl, Wr, bl,
                                                    out, stats, Nn);
    int bnBlocks = (int)((n4 + 255) / 256);
    if (bnBlocks > 8192) bnBlocks = 8192;
    bn_relu_f32_kernel<<<bnBlocks, 256, 0, stream>>>((float4*)out, stats, gamma, beta,
                                                     1.0f / (float)Nn, n4);
}

extern "C" void kernel_launch(void* const* d_in, const int* in_sizes, int n_in,
                              void* d_out, int out_size, void* d_ws, size_t ws_size,
                              hipStream_t stream) {
    (void)n_in; (void)out_size;
    const float* x     = (const float*)d_in[0];
    const int*   ei    = (const int*)d_in[1];
    const float* W0_l  = (const float*)d_in[2];
    const float* b0_l  = (const float*)d_in[3];
    const float* W0_r  = (const float*)d_in[4];
    const float* g0    = (const float*)d_in[5];
    const float* be0   = (const float*)d_in[6];
    const float* W1_l  = (const float*)d_in[7];
    const float* b1_l  = (const float*)d_in[8];
    const float* W1_r  = (const float*)d_in[9];
    const float* g1    = (const float*)d_in[10];
    const float* be1   = (const float*)d_in[11];

    int Nn = in_sizes[0] / 128;
    int Ee = in_sizes[1] / 2;
    long n4 = (long)Nn * 32;                   // float4 / uint2 row-elems
    float inv_n = 1.0f / (float)Nn;

    char* p = (char*)d_ws;
    unsigned short* xy16 = (unsigned short*)p;  p += (size_t)Nn * 128 * 2;  // x16, later y16
    unsigned short* agg16 = (unsigned short*)p; p += (size_t)Nn * 128 * 2;
    float* stats = (float*)p;                   p += 256 * sizeof(float);
    unsigned short* Wt0 = (unsigned short*)p;   p += 128 * 256 * 2;
    unsigned short* Wt1 = (unsigned short*)p;   p += 128 * 256 * 2;
    int* head4 = (int*)p;                       p += (size_t)Nn * 4 * sizeof(int);
    uint2* pair = (uint2*)p;                    p += (size_t)Ee * sizeof(uint2);
    size_t needed = (size_t)(p - (char*)d_ws);
    float* out = (float*)d_out;

    if (ws_size >= needed) {
        // ---- bf16 MFMA path ----
        int cvB = (int)((n4 + 255) / 256);
        if (cvB > 4096) cvB = 4096;
        f32_to_bf16_kernel<<<cvB, 256, 0, stream>>>((const float4*)x, (uint2*)xy16, n4);
        wt_prep2_kernel<<<256, 256, 0, stream>>>(W0_l, W0_r, Wt0, W1_l, W1_r, Wt1);
        init_head_kernel<<<(Nn * 4 + 255) / 256, 256, 0, stream>>>(head4, Nn * 4);
        link_kernel<<<(Ee + 255) / 256, 256, 0, stream>>>(ei, head4, pair, Ee);

        int bnB = (int)((n4 + 255) / 256);
        if (bnB > 8192) bnB = 8192;

        // layer 1: h1 -> d_out (scratch), y1(bf16) -> xy16 (x16 dead after gemm)
        gather_max_ll16_kernel<<<(Nn * 16 + 255) / 256, 256, 0, stream>>>(
            (const uint4*)xy16, head4, pair, (uint4*)agg16, stats, Nn);
        gemm_bf16_kernel<<<(Nn + 127) / 128, 256, 0, stream>>>(agg16, xy16, Wt0, b0_l,
                                                               out, stats, Nn);
        bn_relu_tobf16_kernel<<<bnB, 256, 0, stream>>>((const float4*)out, stats, g0, be0,
                                                       inv_n, (uint2*)xy16, n4);
        // layer 2: h2 -> d_out, final BN+ReLU in place (fp32)
        gather_max_ll16_kernel<<<(Nn * 16 + 255) / 256, 256, 0, stream>>>(
            (const uint4*)xy16, head4, pair, (uint4*)agg16, stats, Nn);
        gemm_bf16_kernel<<<(Nn + 127) / 128, 256, 0, stream>>>(agg16, xy16, Wt1, b1_l,
                                                               out, stats, Nn);
        bn_relu_f32_kernel<<<bnB, 256, 0, stream>>>((float4*)out, stats, g1, be1,
                                                    inv_n, n4);
    } else {
        // ---- fallback: fp32 atomic path ----
        float* agg = (float*)d_ws;
        float* fstats = (float*)((char*)d_ws + (size_t)Nn * 128 * sizeof(float));
        run_layer_atomic(x, ei, Nn, Ee, W0_l, b0_l, W0_r, g0, be0,
                         agg, fstats, out, stream);
        run_layer_atomic(out, ei, Nn, Ee, W1_l, b1_l, W1_r, g1, be1,
                         agg, fstats, out, stream);
    }
}

// Round 8
// 397.367 us; speedup vs baseline: 1.0566x; 1.0566x over previous
//
#include <hip/hip_runtime.h>
#include <stdint.h>

#define EPS_BN 1e-5f

typedef __attribute__((ext_vector_type(8))) short short8v;   // 8 bf16 = 4 VGPR
typedef __attribute__((ext_vector_type(4))) float f32x4;     // MFMA accumulator

__device__ __forceinline__ unsigned rne_bf16(float f) {      // round-to-nearest-even
    unsigned u = __float_as_uint(f);
    return (u + 0x7FFFu + ((u >> 16) & 1u)) >> 16;
}

// ============================================================================
// prep: fp32 -> bf16 feature conversion, weight transpose+concat to bf16
// ============================================================================
extern "C" __global__ __launch_bounds__(256)
void f32_to_bf16_kernel(const float4* __restrict__ in, uint2* __restrict__ out, long n4) {
    long i = (long)blockIdx.x * 256 + threadIdx.x;
    long stride = (long)gridDim.x * 256;
    for (; i < n4; i += stride) {
        float4 v = in[i];
        uint2 o;
        o.x = rne_bf16(v.x) | (rne_bf16(v.y) << 16);
        o.y = rne_bf16(v.z) | (rne_bf16(v.w) << 16);
        out[i] = o;
    }
}

// Wt[col][k] for both layers in one launch: blocks 0-127 -> Wt0, 128-255 -> Wt1
extern "C" __global__ __launch_bounds__(256)
void wt_prep2_kernel(const float* __restrict__ Wl0, const float* __restrict__ Wr0,
                     unsigned short* __restrict__ Wt0,
                     const float* __restrict__ Wl1, const float* __restrict__ Wr1,
                     unsigned short* __restrict__ Wt1) {
    int b = blockIdx.x;
    const float* Wl = (b < 128) ? Wl0 : Wl1;
    const float* Wr = (b < 128) ? Wr0 : Wr1;
    unsigned short* Wt = (b < 128) ? Wt0 : Wt1;
    int idx = (b & 127) * 256 + threadIdx.x;       // 128*256 = 32768 per layer
    int col = idx >> 8, k = idx & 255;
    float v = (k < 128) ? Wl[(size_t)k * 128 + col] : Wr[(size_t)(k - 128) * 128 + col];
    Wt[(size_t)col * 256 + k] = (unsigned short)rne_bf16(v);
}

// ============================================================================
// linked-list build (once; shared by both layers)
//   head[dst] -> most recent edge, pair[e] = (src, prev edge with same dst)
// ============================================================================
extern "C" __global__ __launch_bounds__(256)
void init_head_kernel(int* __restrict__ head, int n) {
    int i = blockIdx.x * 256 + threadIdx.x;
    if (i < n) head[i] = -1;
}

extern "C" __global__ __launch_bounds__(256)
void link_kernel(const int* __restrict__ ei, int* __restrict__ head,
                 uint2* __restrict__ pair, int E) {
    int e = blockIdx.x * 256 + threadIdx.x;
    if (e < E) {
        int src = ei[e];
        int dst = ei[E + e];
        int old = atomicExch(&head[dst], e);
        uint2 p; p.x = (unsigned)src; p.y = (unsigned)old;
        pair[e] = p;                 // coalesced 8B write
    }
}

// ============================================================================
// gather-max (layer 1): 16 lanes/node, uint4 (8 bf16 = 16B) per lane.
// fmax trick: hi bf16 compared as raw u32-as-float (low-16 garbage is sub-ulp;
// ties truncate identically). lo bf16 via exact (u<<16).
// Also zeroes stats0[0..255] from block 0.
// ============================================================================
extern "C" __global__ __launch_bounds__(256, 8)
void gather_max_ll16_kernel(const uint4* __restrict__ x16r, const int* __restrict__ head,
                            const uint2* __restrict__ pair,
                            uint4* __restrict__ agg16, float* __restrict__ stats, int Nn) {
    if (blockIdx.x == 0 && threadIdx.x < 256) stats[threadIdx.x] = 0.0f;
    int t = blockIdx.x * 256 + threadIdx.x;
    int node = t >> 4;
    if (node >= Nn) return;
    int lane = t & 15;
    int e = head[node];
    uint4 out;
    if (e >= 0) {
        uint2 p = pair[e];
        uint4 r = x16r[(size_t)p.x * 16 + lane];
        float a0 = __uint_as_float(r.x << 16), a1 = __uint_as_float(r.x);
        float a2 = __uint_as_float(r.y << 16), a3 = __uint_as_float(r.y);
        float a4 = __uint_as_float(r.z << 16), a5 = __uint_as_float(r.z);
        float a6 = __uint_as_float(r.w << 16), a7 = __uint_as_float(r.w);
        int en = (int)p.y;
        while (en >= 0) {
            uint2 pn = pair[en];                       // single dependent 8B load
            uint4 v = x16r[(size_t)pn.x * 16 + lane];  // row load, overlaps chase
            en = (int)pn.y;
            a0 = fmaxf(a0, __uint_as_float(v.x << 16));
            a1 = fmaxf(a1, __uint_as_float(v.x));
            a2 = fmaxf(a2, __uint_as_float(v.y << 16));
            a3 = fmaxf(a3, __uint_as_float(v.y));
            a4 = fmaxf(a4, __uint_as_float(v.z << 16));
            a5 = fmaxf(a5, __uint_as_float(v.z));
            a6 = fmaxf(a6, __uint_as_float(v.w << 16));
            a7 = fmaxf(a7, __uint_as_float(v.w));
        }
        out.x = (__float_as_uint(a0) >> 16) | (__float_as_uint(a1) & 0xFFFF0000u);
        out.y = (__float_as_uint(a2) >> 16) | (__float_as_uint(a3) & 0xFFFF0000u);
        out.z = (__float_as_uint(a4) >> 16) | (__float_as_uint(a5) & 0xFFFF0000u);
        out.w = (__float_as_uint(a6) >> 16) | (__float_as_uint(a7) & 0xFFFF0000u);
    } else {
        out.x = out.y = out.z = out.w = 0u;   // PyG fills empty segments with 0
    }
    agg16[(size_t)node * 16 + lane] = out;
}

// ============================================================================
// BN scale/shift helper (per-block, into LDS)
// ============================================================================
__device__ __forceinline__ void bn_make_ss(const float* __restrict__ stats,
                                           const float* __restrict__ gamma,
                                           const float* __restrict__ beta,
                                           float inv_n, float* s_ss) {
    int t = threadIdx.x;
    if (t < 128) {
        float mu = stats[t] * inv_n;
        float var = stats[128 + t] * inv_n - mu * mu;
        float sc = gamma[t] * rsqrtf(var + EPS_BN);
        s_ss[t] = sc;
        s_ss[128 + t] = beta[t] - mu * sc;
    }
    __syncthreads();
}

// ============================================================================
// gather-max + fused BN0 (layer 2):
//   agg2 = relu(bn0(max over neighbors of h1))   [monotone since gamma0 > 0]
//   y1   = relu(bn0(h1[node]))                   [lin_r input for gemm2]
// reads raw bf16 h1 rows; applies relu(bn) once post-aggregation.
// Also zeroes stats1[0..255] from block 0.
// ============================================================================
extern "C" __global__ __launch_bounds__(256, 8)
void gather_max_bn_kernel(const uint4* __restrict__ h1r, const int* __restrict__ head,
                          const uint2* __restrict__ pair,
                          const float* __restrict__ stats0,
                          const float* __restrict__ gamma, const float* __restrict__ beta,
                          float inv_n,
                          uint4* __restrict__ agg16, uint4* __restrict__ y16,
                          float* __restrict__ stats1, int Nn) {
    __shared__ float s_ss[256];
    bn_make_ss(stats0, gamma, beta, inv_n, s_ss);          // all threads, has sync
    if (blockIdx.x == 0 && threadIdx.x < 256) stats1[threadIdx.x] = 0.0f;

    int t = blockIdx.x * 256 + threadIdx.x;
    int node = t >> 4;
    if (node >= Nn) return;
    int lane = t & 15;

    float sc[8], sh[8];
#pragma unroll
    for (int j = 0; j < 8; ++j) {
        sc[j] = s_ss[lane * 8 + j];
        sh[j] = s_ss[128 + lane * 8 + j];
    }

    // ---- own row -> y1 = relu(bn(h1[node])) ----
    {
        uint4 r = h1r[(size_t)node * 16 + lane];
        float v0 = __uint_as_float(r.x << 16), v1 = __uint_as_float(r.x & 0xFFFF0000u);
        float v2 = __uint_as_float(r.y << 16), v3 = __uint_as_float(r.y & 0xFFFF0000u);
        float v4 = __uint_as_float(r.z << 16), v5 = __uint_as_float(r.z & 0xFFFF0000u);
        float v6 = __uint_as_float(r.w << 16), v7 = __uint_as_float(r.w & 0xFFFF0000u);
        v0 = fmaxf(fmaf(v0, sc[0], sh[0]), 0.f);
        v1 = fmaxf(fmaf(v1, sc[1], sh[1]), 0.f);
        v2 = fmaxf(fmaf(v2, sc[2], sh[2]), 0.f);
        v3 = fmaxf(fmaf(v3, sc[3], sh[3]), 0.f);
        v4 = fmaxf(fmaf(v4, sc[4], sh[4]), 0.f);
        v5 = fmaxf(fmaf(v5, sc[5], sh[5]), 0.f);
        v6 = fmaxf(fmaf(v6, sc[6], sh[6]), 0.f);
        v7 = fmaxf(fmaf(v7, sc[7], sh[7]), 0.f);
        uint4 o;
        o.x = rne_bf16(v0) | (rne_bf16(v1) << 16);
        o.y = rne_bf16(v2) | (rne_bf16(v3) << 16);
        o.z = rne_bf16(v4) | (rne_bf16(v5) << 16);
        o.w = rne_bf16(v6) | (rne_bf16(v7) << 16);
        y16[(size_t)node * 16 + lane] = o;
    }

    // ---- neighbor max (raw), then relu(bn(.)) once ----
    int e = head[node];
    uint4 out;
    if (e >= 0) {
        uint2 p = pair[e];
        uint4 r = h1r[(size_t)p.x * 16 + lane];
        float a0 = __uint_as_float(r.x << 16), a1 = __uint_as_float(r.x);
        float a2 = __uint_as_float(r.y << 16), a3 = __uint_as_float(r.y);
        float a4 = __uint_as_float(r.z << 16), a5 = __uint_as_float(r.z);
        float a6 = __uint_as_float(r.w << 16), a7 = __uint_as_float(r.w);
        int en = (int)p.y;
        while (en >= 0) {
            uint2 pn = pair[en];
            uint4 v = h1r[(size_t)pn.x * 16 + lane];
            en = (int)pn.y;
            a0 = fmaxf(a0, __uint_as_float(v.x << 16));
            a1 = fmaxf(a1, __uint_as_float(v.x));
            a2 = fmaxf(a2, __uint_as_float(v.y << 16));
            a3 = fmaxf(a3, __uint_as_float(v.y));
            a4 = fmaxf(a4, __uint_as_float(v.z << 16));
            a5 = fmaxf(a5, __uint_as_float(v.z));
            a6 = fmaxf(a6, __uint_as_float(v.w << 16));
            a7 = fmaxf(a7, __uint_as_float(v.w));
        }
        // clean hi-garbage before the affine map
        a1 = __uint_as_float(__float_as_uint(a1) & 0xFFFF0000u);
        a3 = __uint_as_float(__float_as_uint(a3) & 0xFFFF0000u);
        a5 = __uint_as_float(__float_as_uint(a5) & 0xFFFF0000u);
        a7 = __uint_as_float(__float_as_uint(a7) & 0xFFFF0000u);
        a0 = fmaxf(fmaf(a0, sc[0], sh[0]), 0.f);
        a1 = fmaxf(fmaf(a1, sc[1], sh[1]), 0.f);
        a2 = fmaxf(fmaf(a2, sc[2], sh[2]), 0.f);
        a3 = fmaxf(fmaf(a3, sc[3], sh[3]), 0.f);
        a4 = fmaxf(fmaf(a4, sc[4], sh[4]), 0.f);
        a5 = fmaxf(fmaf(a5, sc[5], sh[5]), 0.f);
        a6 = fmaxf(fmaf(a6, sc[6], sh[6]), 0.f);
        a7 = fmaxf(fmaf(a7, sc[7], sh[7]), 0.f);
        out.x = rne_bf16(a0) | (rne_bf16(a1) << 16);
        out.y = rne_bf16(a2) | (rne_bf16(a3) << 16);
        out.z = rne_bf16(a4) | (rne_bf16(a5) << 16);
        out.w = rne_bf16(a6) | (rne_bf16(a7) << 16);
    } else {
        out.x = out.y = out.z = out.w = 0u;   // PyG 0-fill (pre-GEMM, no BN)
    }
    agg16[(size_t)node * 16 + lane] = out;
}

// ============================================================================
// MFMA GEMM: acc = [agg16 | xin16] @ Wt^T + bias, fused BN col-stats.
// OUT_BF16=1 -> write h as bf16 (2B stores); else fp32.
// 256 thr = 4 waves (2x2), BM=128, BN=128, per wave 64x64 (4x4 frags 16x16).
// ============================================================================
template <int OUT_BF16>
__device__ __forceinline__
void gemm_bf16_body(const unsigned short* __restrict__ agg16,
                    const unsigned short* __restrict__ xin16,
                    const unsigned short* __restrict__ Wt,
                    const float* __restrict__ bias,
                    void* __restrict__ hout, float* __restrict__ stats, int nrows) {
    __shared__ float redS[4][128];
    __shared__ float redQ[4][128];

    const int t = threadIdx.x;
    const int w = t >> 6, l = t & 63;
    const int wm = w >> 1, wn = w & 1;
    const int r16 = l & 15, g = l >> 4;
    const int blockRow = blockIdx.x * 128;
    const int colBase = wn * 64;

    f32x4 acc[4][4];
#pragma unroll
    for (int m = 0; m < 4; ++m)
#pragma unroll
        for (int n = 0; n < 4; ++n) acc[m][n] = (f32x4){0.f, 0.f, 0.f, 0.f};

    const short8v az = {0, 0, 0, 0, 0, 0, 0, 0};

#pragma unroll
    for (int kt = 0; kt < 8; ++kt) {
        const unsigned short* Asrc = (kt < 4) ? agg16 : xin16;
        const int kofs = (kt < 4) ? kt * 32 : kt * 32 - 128;

        short8v b[4];
#pragma unroll
        for (int n = 0; n < 4; ++n) {
            int col = colBase + n * 16 + r16;
            b[n] = *(const short8v*)(Wt + (size_t)col * 256 + kt * 32 + g * 8);
        }
        short8v a[4];
#pragma unroll
        for (int m = 0; m < 4; ++m) {
            int row = blockRow + wm * 64 + m * 16 + r16;
            a[m] = (row < nrows)
                 ? *(const short8v*)(Asrc + (size_t)row * 128 + kofs + g * 8)
                 : az;
        }
#pragma unroll
        for (int m = 0; m < 4; ++m)
#pragma unroll
            for (int n = 0; n < 4; ++n)
                acc[m][n] = __builtin_amdgcn_mfma_f32_16x16x32_bf16(a[m], b[n], acc[m][n], 0, 0, 0);
    }

    // ---- epilogue: bias, store h, fused BN stats ----
    for (int i = t; i < 512; i += 256) {
        ((float*)redS)[i] = 0.f;
        ((float*)redQ)[i] = 0.f;
    }
    __syncthreads();

    float bcol[4];
#pragma unroll
    for (int n = 0; n < 4; ++n) bcol[n] = bias[colBase + n * 16 + r16];

    float s4[4] = {0.f, 0.f, 0.f, 0.f};
    float q4[4] = {0.f, 0.f, 0.f, 0.f};
#pragma unroll
    for (int m = 0; m < 4; ++m) {
#pragma unroll
        for (int reg = 0; reg < 4; ++reg) {
            int row = blockRow + wm * 64 + m * 16 + g * 4 + reg;   // C/D: row=(l>>4)*4+reg
            if (row < nrows) {
#pragma unroll
                for (int n = 0; n < 4; ++n) {
                    float o = acc[m][n][reg] + bcol[n];
                    int col = colBase + n * 16 + r16;               // col=l&15
                    if (OUT_BF16)
                        ((unsigned short*)hout)[(size_t)row * 128 + col] =
                            (unsigned short)rne_bf16(o);
                    else
                        ((float*)hout)[(size_t)row * 128 + col] = o;
                    s4[n] += o;
                    q4[n] += o * o;
                }
            }
        }
    }
#pragma unroll
    for (int n = 0; n < 4; ++n) {     // reduce over the 4 k-groups (same col)
        s4[n] += __shfl_xor(s4[n], 16, 64);
        s4[n] += __shfl_xor(s4[n], 32, 64);
        q4[n] += __shfl_xor(q4[n], 16, 64);
        q4[n] += __shfl_xor(q4[n], 32, 64);
    }
    if (g == 0) {
#pragma unroll
        for (int n = 0; n < 4; ++n) {
            redS[w][colBase + n * 16 + r16] = s4[n];
            redQ[w][colBase + n * 16 + r16] = q4[n];
        }
    }
    __syncthreads();
    if (t < 128) {
        float s = redS[0][t] + redS[1][t] + redS[2][t] + redS[3][t];
        float q = redQ[0][t] + redQ[1][t] + redQ[2][t] + redQ[3][t];
        atomicAdd(&stats[t], s);
        atomicAdd(&stats[128 + t], q);
    }
}

extern "C" __global__ __launch_bounds__(256)
void gemm_bf16_out16_kernel(const unsigned short* __restrict__ agg16,
                            const unsigned short* __restrict__ xin16,
                            const unsigned short* __restrict__ Wt,
                            const float* __restrict__ bias,
                            unsigned short* __restrict__ h, float* __restrict__ stats,
                            int nrows) {
    gemm_bf16_body<1>(agg16, xin16, Wt, bias, h, stats, nrows);
}

extern "C" __global__ __launch_bounds__(256)
void gemm_bf16_out32_kernel(const unsigned short* __restrict__ agg16,
                            const unsigned short* __restrict__ xin16,
                            const unsigned short* __restrict__ Wt,
                            const float* __restrict__ bias,
                            float* __restrict__ h, float* __restrict__ stats,
                            int nrows) {
    gemm_bf16_body<0>(agg16, xin16, Wt, bias, h, stats, nrows);
}

// ============================================================================
// final BN+ReLU in place fp32 (finalize fused per block)
// ============================================================================
extern "C" __global__ __launch_bounds__(256)
void bn_relu_f32_kernel(float4* __restrict__ h, const float* __restrict__ stats,
                        const float* __restrict__ gamma, const float* __restrict__ beta,
                        float inv_n, long n4) {
    __shared__ float s_ss[256];
    bn_make_ss(stats, gamma, beta, inv_n, s_ss);
    long i = (long)blockIdx.x * blockDim.x + threadIdx.x;
    long stride = (long)gridDim.x * blockDim.x;
    for (; i < n4; i += stride) {
        int c4 = (int)(i & 31) * 4;
        float4 v = h[i];
        v.x = fmaxf(fmaf(v.x, s_ss[c4 + 0], s_ss[128 + c4 + 0]), 0.f);
        v.y = fmaxf(fmaf(v.y, s_ss[c4 + 1], s_ss[128 + c4 + 1]), 0.f);
        v.z = fmaxf(fmaf(v.z, s_ss[c4 + 2], s_ss[128 + c4 + 2]), 0.f);
        v.w = fmaxf(fmaf(v.w, s_ss[c4 + 3], s_ss[128 + c4 + 3]), 0.f);
        h[i] = v;
    }
}

// ============================================================================
// fallback path (fp32 atomic scatter-max + VALU GEMM) — only if ws too small
// ============================================================================
__device__ __forceinline__ unsigned map_f(float f) {
    unsigned u = __float_as_uint(f);
    return (u & 0x80000000u) ? ~u : (u | 0x80000000u);
}
__device__ __forceinline__ float unmap_f(unsigned m) {
    return (m & 0x80000000u) ? __uint_as_float(m & 0x7FFFFFFFu) : __uint_as_float(~m);
}

extern "C" __global__ __launch_bounds__(256)
void init_sentinel_kernel(uint4* __restrict__ agg, long n4) {
    uint4 z = {0u, 0u, 0u, 0u};
    long i = (long)blockIdx.x * blockDim.x + threadIdx.x;
    long stride = (long)gridDim.x * blockDim.x;
    for (; i < n4; i += stride) agg[i] = z;
}

extern "C" __global__ __launch_bounds__(256)
void scatter_max_kernel(const float4* __restrict__ xin, const int* __restrict__ ei,
                        unsigned* __restrict__ agg, int E) {
    int t = blockIdx.x * 256 + threadIdx.x;
    int e = t >> 5;
    if (e >= E) return;
    int f4 = t & 31;
    int src = ei[e];
    int dst = ei[E + e];
    float4 v = xin[(size_t)src * 32 + f4];
    unsigned* p = agg + (size_t)dst * 128 + (size_t)f4 * 4;
    atomicMax(p + 0, map_f(v.x));
    atomicMax(p + 1, map_f(v.y));
    atomicMax(p + 2, map_f(v.z));
    atomicMax(p + 3, map_f(v.w));
}

extern "C" __global__ __launch_bounds__(256)
void unmap_kernel(unsigned* __restrict__ agg, long n) {
    long i = (long)blockIdx.x * blockDim.x + threadIdx.x;
    long stride = (long)gridDim.x * blockDim.x;
    for (; i < n; i += stride) {
        unsigned u = agg[i];
        agg[i] = __float_as_uint(u ? unmap_f(u) : 0.0f);
    }
}

extern "C" __global__
void zero_stats_kernel(float* __restrict__ stats) {
    stats[threadIdx.x] = 0.0f;
}

extern "C" __global__ __launch_bounds__(256)
void gemm_kernel(const float* __restrict__ agg, const float* __restrict__ xin,
                 const float* __restrict__ Wl, const float* __restrict__ Wr,
                 const float* __restrict__ bias, float* __restrict__ h,
                 float* __restrict__ stats, int nrows) {
    __shared__ __align__(16) float As[64][36];
    __shared__ __align__(16) float Bs[32][136];
    __shared__ float redS[4][128];
    __shared__ float redQ[4][128];

    const int t = threadIdx.x;
    const int tx = t & 15;
    const int ty = t >> 4;
    const int tx8 = tx * 8;
    const int ty4 = ty * 4;
    const int blockRow = blockIdx.x * 64;

    float acc[4][8];
#pragma unroll
    for (int j = 0; j < 4; ++j)
#pragma unroll
        for (int c = 0; c < 8; ++c) acc[j][c] = 0.0f;

    for (int kt = 0; kt < 8; ++kt) {
        const int k0 = kt * 32;
        const bool isAgg = (kt < 4);
        const float* W = isAgg ? Wl : Wr;
        const float* Asrc = isAgg ? agg : xin;
        const int kw = isAgg ? k0 : (k0 - 128);

#pragma unroll
        for (int it = 0; it < 4; ++it) {
            int idx = t + it * 256;
            int kr = idx >> 5, cq = idx & 31;
            float4 ww = *(const float4*)&W[(size_t)(kw + kr) * 128 + cq * 4];
            *(float4*)&Bs[kr][cq * 4] = ww;
        }
#pragma unroll
        for (int it = 0; it < 2; ++it) {
            int idx = t + it * 256;
            int r = idx >> 3, kq = idx & 7;
            int row_g = blockRow + r;
            float4 a = {0.f, 0.f, 0.f, 0.f};
            if (row_g < nrows)
                a = *(const float4*)&Asrc[(size_t)row_g * 128 + kw + kq * 4];
            *(float4*)&As[r][kq * 4] = a;
        }
        __syncthreads();

#pragma unroll
        for (int kk = 0; kk < 32; ++kk) {
            float aa[4];
            aa[0] = As[ty4 + 0][kk];
            aa[1] = As[ty4 + 1][kk];
            aa[2] = As[ty4 + 2][kk];
            aa[3] = As[ty4 + 3][kk];
            float4 b0 = *(const float4*)&Bs[kk][tx8];
            float4 b1 = *(const float4*)&Bs[kk][tx8 + 4];
            float bb[8] = {b0.x, b0.y, b0.z, b0.w, b1.x, b1.y, b1.z, b1.w};
#pragma unroll
            for (int j = 0; j < 4; ++j)
#pragma unroll
                for (int c = 0; c < 8; ++c)
                    acc[j][c] = fmaf(aa[j], bb[c], acc[j][c]);
        }
        __syncthreads();
    }

    float bv[8];
#pragma unroll
    for (int c = 0; c < 8; ++c) bv[c] = bias[tx8 + c];

    float s_loc[8], q_loc[8];
#pragma unroll
    for (int c = 0; c < 8; ++c) { s_loc[c] = 0.f; q_loc[c] = 0.f; }

#pragma unroll
    for (int j = 0; j < 4; ++j) {
        int row = blockRow + ty4 + j;
        if (row < nrows) {
            float o[8];
#pragma unroll
            for (int c = 0; c < 8; ++c) {
                o[c] = acc[j][c] + bv[c];
                s_loc[c] += o[c];
                q_loc[c] += o[c] * o[c];
            }
            float4 o0 = {o[0], o[1], o[2], o[3]};
            float4 o1 = {o[4], o[5], o[6], o[7]};
            *(float4*)&h[(size_t)row * 128 + tx8] = o0;
            *(float4*)&h[(size_t)row * 128 + tx8 + 4] = o1;
        }
    }

#pragma unroll
    for (int c = 0; c < 8; ++c) {
        s_loc[c] += __shfl_xor(s_loc[c], 16, 64);
        s_loc[c] += __shfl_xor(s_loc[c], 32, 64);
        q_loc[c] += __shfl_xor(q_loc[c], 16, 64);
        q_loc[c] += __shfl_xor(q_loc[c], 32, 64);
    }
    int wave = t >> 6;
    if ((t & 63) < 16) {
#pragma unroll
        for (int c = 0; c < 8; ++c) {
            redS[wave][tx8 + c] = s_loc[c];
            redQ[wave][tx8 + c] = q_loc[c];
        }
    }
    __syncthreads();
    if (t < 128) {
        float s = redS[0][t] + redS[1][t] + redS[2][t] + redS[3][t];
        float q = redQ[0][t] + redQ[1][t] + redQ[2][t] + redQ[3][t];
        atomicAdd(&stats[t], s);
        atomicAdd(&stats[128 + t], q);
    }
}

static void run_layer_atomic(const float* in_feat, const int* ei, int Nn, int Ee,
                             const float* Wl, const float* bl, const float* Wr,
                             const float* gamma, const float* beta,
                             float* agg, float* stats, float* out, hipStream_t stream) {
    long aggN = (long)Nn * 128;
    long n4 = aggN / 4;

    zero_stats_kernel<<<1, 256, 0, stream>>>(stats);
    int initBlocks = (int)((n4 + 255) / 256);
    if (initBlocks > 4096) initBlocks = 4096;
    init_sentinel_kernel<<<initBlocks, 256, 0, stream>>>((uint4*)agg, n4);
    int sb = (int)(((long)Ee * 32 + 255) / 256);
    scatter_max_kernel<<<sb, 256, 0, stream>>>((const float4*)in_feat, ei,
                                               (unsigned*)agg, Ee);
    int ub = (int)((aggN + 255) / 256);
    if (ub > 8192) ub = 8192;
    unmap_kernel<<<ub, 256, 0, stream>>>((unsigned*)agg, aggN);
    gemm_kernel<<<(Nn + 63) / 64, 256, 0, stream>>>(agg, in_feat, Wl, Wr, bl,
                                                    out, stats, Nn);
    int bnBlocks = (int)((n4 + 255) / 256);
    if (bnBlocks > 8192) bnBlocks = 8192;
    bn_relu_f32_kernel<<<bnBlocks, 256, 0, stream>>>((float4*)out, stats, gamma, beta,
                                                     1.0f / (float)Nn, n4);
}

// ============================================================================
// host-side orchestration
// ============================================================================
extern "C" void kernel_launch(void* const* d_in, const int* in_sizes, int n_in,
                              void* d_out, int out_size, void* d_ws, size_t ws_size,
                              hipStream_t stream) {
    (void)n_in; (void)out_size;
    const float* x     = (const float*)d_in[0];
    const int*   ei    = (const int*)d_in[1];
    const float* W0_l  = (const float*)d_in[2];
    const float* b0_l  = (const float*)d_in[3];
    const float* W0_r  = (const float*)d_in[4];
    const float* g0    = (const float*)d_in[5];
    const float* be0   = (const float*)d_in[6];
    const float* W1_l  = (const float*)d_in[7];
    const float* b1_l  = (const float*)d_in[8];
    const float* W1_r  = (const float*)d_in[9];
    const float* g1    = (const float*)d_in[10];
    const float* be1   = (const float*)d_in[11];

    int Nn = in_sizes[0] / 128;
    int Ee = in_sizes[1] / 2;
    long n4 = (long)Nn * 32;                   // float4 / uint2 row-elems
    float inv_n = 1.0f / (float)Nn;

    char* p = (char*)d_ws;
    unsigned short* xy16 = (unsigned short*)p;  p += (size_t)Nn * 128 * 2;  // x16, later y16
    unsigned short* agg16 = (unsigned short*)p; p += (size_t)Nn * 128 * 2;
    float* stats0 = (float*)p;                  p += 256 * sizeof(float);
    float* stats1 = (float*)p;                  p += 256 * sizeof(float);
    unsigned short* Wt0 = (unsigned short*)p;   p += 128 * 256 * 2;
    unsigned short* Wt1 = (unsigned short*)p;   p += 128 * 256 * 2;
    int* head = (int*)p;                        p += (size_t)Nn * sizeof(int);
    uint2* pair = (uint2*)p;                    p += (size_t)Ee * sizeof(uint2);
    size_t needed = (size_t)(p - (char*)d_ws);
    float* out = (float*)d_out;
    unsigned short* h1 = (unsigned short*)d_out;   // h1-bf16 parked in d_out (dead by gemm2)

    if (ws_size >= needed) {
        // ---- bf16 MFMA path ----
        int cvB = (int)((n4 + 255) / 256);
        if (cvB > 4096) cvB = 4096;
        f32_to_bf16_kernel<<<cvB, 256, 0, stream>>>((const float4*)x, (uint2*)xy16, n4);
        wt_prep2_kernel<<<256, 256, 0, stream>>>(W0_l, W0_r, Wt0, W1_l, W1_r, Wt1);
        init_head_kernel<<<(Nn + 255) / 256, 256, 0, stream>>>(head, Nn);
        link_kernel<<<(Ee + 255) / 256, 256, 0, stream>>>(ei, head, pair, Ee);

        int gB = (Nn * 16 + 255) / 256;
        int mB = (Nn + 127) / 128;
        int bnB = (int)((n4 + 255) / 256);
        if (bnB > 8192) bnB = 8192;

        // layer 1: agg1 <- max x16; h1(bf16) -> d_out; stats0
        gather_max_ll16_kernel<<<gB, 256, 0, stream>>>(
            (const uint4*)xy16, head, pair, (uint4*)agg16, stats0, Nn);
        gemm_bf16_out16_kernel<<<mB, 256, 0, stream>>>(agg16, xy16, Wt0, b0_l,
                                                       h1, stats0, Nn);
        // layer 2: agg2 = relu(bn0(max h1)), y1 = relu(bn0(h1)) -> xy16; stats1 zeroed
        gather_max_bn_kernel<<<gB, 256, 0, stream>>>(
            (const uint4*)h1, head, pair, stats0, g0, be0, inv_n,
            (uint4*)agg16, (uint4*)xy16, stats1, Nn);
        gemm_bf16_out32_kernel<<<mB, 256, 0, stream>>>(agg16, xy16, Wt1, b1_l,
                                                       out, stats1, Nn);
        bn_relu_f32_kernel<<<bnB, 256, 0, stream>>>((float4*)out, stats1, g1, be1,
                                                    inv_n, n4);
    } else {
        // ---- fallback: fp32 atomic path ----
        float* agg = (float*)d_ws;
        float* fstats = (float*)((char*)d_ws + (size_t)Nn * 128 * sizeof(float));
        run_layer_atomic(x, ei, Nn, Ee, W0_l, b0_l, W0_r, g0, be0,
                         agg, fstats, out, stream);
        run_layer_atomic(out, ei, Nn, Ee, W1_l, b1_l, W1_r, g1, be1,
                         agg, fstats, out, stream);
    }
}

// Round 9
// 393.400 us; speedup vs baseline: 1.0673x; 1.0101x over previous
//
#include <hip/hip_runtime.h>
#include <stdint.h>

#define EPS_BN 1e-5f

typedef __attribute__((ext_vector_type(8))) short short8v;   // 8 bf16 = 4 VGPR
typedef __attribute__((ext_vector_type(4))) float f32x4;     // MFMA accumulator

__device__ __forceinline__ unsigned rne_bf16(float f) {      // round-to-nearest-even
    unsigned u = __float_as_uint(f);
    return (u + 0x7FFFu + ((u >> 16) & 1u)) >> 16;
}

// ============================================================================
// merged prep: [0,cvB) x->bf16 | [cvB,cvB+256) wt0/wt1 | [cvB+256,...) head=-1
// ============================================================================
extern "C" __global__ __launch_bounds__(256)
void prep_kernel(const float4* __restrict__ x, uint2* __restrict__ x16, long n4, int cvB,
                 const float* __restrict__ Wl0, const float* __restrict__ Wr0,
                 unsigned short* __restrict__ Wt0,
                 const float* __restrict__ Wl1, const float* __restrict__ Wr1,
                 unsigned short* __restrict__ Wt1,
                 int* __restrict__ head, int Nn) {
    int b = blockIdx.x;
    if (b < cvB) {
        long i = (long)b * 256 + threadIdx.x;
        long stride = (long)cvB * 256;
        for (; i < n4; i += stride) {
            float4 v = x[i];
            uint2 o;
            o.x = rne_bf16(v.x) | (rne_bf16(v.y) << 16);
            o.y = rne_bf16(v.z) | (rne_bf16(v.w) << 16);
            x16[i] = o;
        }
    } else if (b < cvB + 256) {
        int wb = b - cvB;
        const float* Wl = (wb < 128) ? Wl0 : Wl1;
        const float* Wr = (wb < 128) ? Wr0 : Wr1;
        unsigned short* Wt = (wb < 128) ? Wt0 : Wt1;
        int idx = (wb & 127) * 256 + threadIdx.x;
        int col = idx >> 8, k = idx & 255;
        float v = (k < 128) ? Wl[(size_t)k * 128 + col]
                            : Wr[(size_t)(k - 128) * 128 + col];
        Wt[(size_t)col * 256 + k] = (unsigned short)rne_bf16(v);
    } else {
        int i = (b - cvB - 256) * 256 + threadIdx.x;
        if (i < Nn) head[i] = -1;
    }
}

// ============================================================================
// linked-list build: head[dst] -> latest edge, pair[e] = (src, prev same-dst)
// ============================================================================
extern "C" __global__ __launch_bounds__(256)
void link_kernel(const int* __restrict__ ei, int* __restrict__ head,
                 uint2* __restrict__ pair, int E) {
    int e = blockIdx.x * 256 + threadIdx.x;
    if (e < E) {
        int src = ei[e];
        int dst = ei[E + e];
        int old = atomicExch(&head[dst], e);
        uint2 p; p.x = (unsigned)src; p.y = (unsigned)old;
        pair[e] = p;                 // coalesced 8B write
    }
}

// ============================================================================
// gather-max (layer 1): 16 lanes/node, uint4 (8 bf16 = 16B) per lane.
// fmax trick: hi bf16 compared as raw u32-as-float (low-16 garbage is sub-ulp;
// ties truncate identically). lo bf16 via exact (u<<16).
// Also zeroes stats0[0..255] from block 0.
// ============================================================================
extern "C" __global__ __launch_bounds__(256, 8)
void gather_max_ll16_kernel(const uint4* __restrict__ x16r, const int* __restrict__ head,
                            const uint2* __restrict__ pair,
                            uint4* __restrict__ agg16, float* __restrict__ stats, int Nn) {
    if (blockIdx.x == 0 && threadIdx.x < 256) stats[threadIdx.x] = 0.0f;
    int t = blockIdx.x * 256 + threadIdx.x;
    int node = t >> 4;
    if (node >= Nn) return;
    int lane = t & 15;
    int e = head[node];
    uint4 out;
    if (e >= 0) {
        uint2 p = pair[e];
        uint4 r = x16r[(size_t)p.x * 16 + lane];
        float a0 = __uint_as_float(r.x << 16), a1 = __uint_as_float(r.x);
        float a2 = __uint_as_float(r.y << 16), a3 = __uint_as_float(r.y);
        float a4 = __uint_as_float(r.z << 16), a5 = __uint_as_float(r.z);
        float a6 = __uint_as_float(r.w << 16), a7 = __uint_as_float(r.w);
        int en = (int)p.y;
        while (en >= 0) {
            uint2 pn = pair[en];                       // single dependent 8B load
            uint4 v = x16r[(size_t)pn.x * 16 + lane];  // row load, overlaps chase
            en = (int)pn.y;
            a0 = fmaxf(a0, __uint_as_float(v.x << 16));
            a1 = fmaxf(a1, __uint_as_float(v.x));
            a2 = fmaxf(a2, __uint_as_float(v.y << 16));
            a3 = fmaxf(a3, __uint_as_float(v.y));
            a4 = fmaxf(a4, __uint_as_float(v.z << 16));
            a5 = fmaxf(a5, __uint_as_float(v.z));
            a6 = fmaxf(a6, __uint_as_float(v.w << 16));
            a7 = fmaxf(a7, __uint_as_float(v.w));
        }
        out.x = (__float_as_uint(a0) >> 16) | (__float_as_uint(a1) & 0xFFFF0000u);
        out.y = (__float_as_uint(a2) >> 16) | (__float_as_uint(a3) & 0xFFFF0000u);
        out.z = (__float_as_uint(a4) >> 16) | (__float_as_uint(a5) & 0xFFFF0000u);
        out.w = (__float_as_uint(a6) >> 16) | (__float_as_uint(a7) & 0xFFFF0000u);
    } else {
        out.x = out.y = out.z = out.w = 0u;   // PyG fills empty segments with 0
    }
    agg16[(size_t)node * 16 + lane] = out;
}

// ============================================================================
// gather-max + fused BN0 (layer 2):
//   agg2 = relu(bn0(max over neighbors of h1))   [monotone since gamma0 > 0]
//   y1   = relu(bn0(h1[node]))                   [lin_r input for gemm2]
// scale/shift staged transposed in LDS: ssT[j][lane] -> stride-1, conflict-free.
// Also zeroes stats1[0..255] from block 0.
// ============================================================================
extern "C" __global__ __launch_bounds__(256, 8)
void gather_max_bn_kernel(const uint4* __restrict__ h1r, const int* __restrict__ head,
                          const uint2* __restrict__ pair,
                          const float* __restrict__ stats0,
                          const float* __restrict__ gamma, const float* __restrict__ beta,
                          float inv_n,
                          uint4* __restrict__ agg16, uint4* __restrict__ y16,
                          float* __restrict__ stats1, int Nn) {
    __shared__ float scT[8][17];   // [j][lane] : c = lane*8+j
    __shared__ float shT[8][17];
    {
        int t = threadIdx.x;
        if (t < 128) {
            float mu = stats0[t] * inv_n;
            float var = stats0[128 + t] * inv_n - mu * mu;
            float sc = gamma[t] * rsqrtf(var + EPS_BN);
            scT[t & 7][t >> 3] = sc;
            shT[t & 7][t >> 3] = beta[t] - mu * sc;
        }
        __syncthreads();
    }
    if (blockIdx.x == 0 && threadIdx.x < 256) stats1[threadIdx.x] = 0.0f;

    int t = blockIdx.x * 256 + threadIdx.x;
    int node = t >> 4;
    if (node >= Nn) return;
    int lane = t & 15;

    float sc[8], sh[8];
#pragma unroll
    for (int j = 0; j < 8; ++j) {
        sc[j] = scT[j][lane];      // stride-1 across the 16-lane group
        sh[j] = shT[j][lane];
    }

    // ---- own row -> y1 = relu(bn(h1[node])) ----
    {
        uint4 r = h1r[(size_t)node * 16 + lane];
        float v0 = __uint_as_float(r.x << 16), v1 = __uint_as_float(r.x & 0xFFFF0000u);
        float v2 = __uint_as_float(r.y << 16), v3 = __uint_as_float(r.y & 0xFFFF0000u);
        float v4 = __uint_as_float(r.z << 16), v5 = __uint_as_float(r.z & 0xFFFF0000u);
        float v6 = __uint_as_float(r.w << 16), v7 = __uint_as_float(r.w & 0xFFFF0000u);
        v0 = fmaxf(fmaf(v0, sc[0], sh[0]), 0.f);
        v1 = fmaxf(fmaf(v1, sc[1], sh[1]), 0.f);
        v2 = fmaxf(fmaf(v2, sc[2], sh[2]), 0.f);
        v3 = fmaxf(fmaf(v3, sc[3], sh[3]), 0.f);
        v4 = fmaxf(fmaf(v4, sc[4], sh[4]), 0.f);
        v5 = fmaxf(fmaf(v5, sc[5], sh[5]), 0.f);
        v6 = fmaxf(fmaf(v6, sc[6], sh[6]), 0.f);
        v7 = fmaxf(fmaf(v7, sc[7], sh[7]), 0.f);
        uint4 o;
        o.x = rne_bf16(v0) | (rne_bf16(v1) << 16);
        o.y = rne_bf16(v2) | (rne_bf16(v3) << 16);
        o.z = rne_bf16(v4) | (rne_bf16(v5) << 16);
        o.w = rne_bf16(v6) | (rne_bf16(v7) << 16);
        y16[(size_t)node * 16 + lane] = o;
    }

    // ---- neighbor max (raw), then relu(bn(.)) once ----
    int e = head[node];
    uint4 out;
    if (e >= 0) {
        uint2 p = pair[e];
        uint4 r = h1r[(size_t)p.x * 16 + lane];
        float a0 = __uint_as_float(r.x << 16), a1 = __uint_as_float(r.x);
        float a2 = __uint_as_float(r.y << 16), a3 = __uint_as_float(r.y);
        float a4 = __uint_as_float(r.z << 16), a5 = __uint_as_float(r.z);
        float a6 = __uint_as_float(r.w << 16), a7 = __uint_as_float(r.w);
        int en = (int)p.y;
        while (en >= 0) {
            uint2 pn = pair[en];
            uint4 v = h1r[(size_t)pn.x * 16 + lane];
            en = (int)pn.y;
            a0 = fmaxf(a0, __uint_as_float(v.x << 16));
            a1 = fmaxf(a1, __uint_as_float(v.x));
            a2 = fmaxf(a2, __uint_as_float(v.y << 16));
            a3 = fmaxf(a3, __uint_as_float(v.y));
            a4 = fmaxf(a4, __uint_as_float(v.z << 16));
            a5 = fmaxf(a5, __uint_as_float(v.z));
            a6 = fmaxf(a6, __uint_as_float(v.w << 16));
            a7 = fmaxf(a7, __uint_as_float(v.w));
        }
        // clean hi-garbage before the affine map
        a1 = __uint_as_float(__float_as_uint(a1) & 0xFFFF0000u);
        a3 = __uint_as_float(__float_as_uint(a3) & 0xFFFF0000u);
        a5 = __uint_as_float(__float_as_uint(a5) & 0xFFFF0000u);
        a7 = __uint_as_float(__float_as_uint(a7) & 0xFFFF0000u);
        a0 = fmaxf(fmaf(a0, sc[0], sh[0]), 0.f);
        a1 = fmaxf(fmaf(a1, sc[1], sh[1]), 0.f);
        a2 = fmaxf(fmaf(a2, sc[2], sh[2]), 0.f);
        a3 = fmaxf(fmaf(a3, sc[3], sh[3]), 0.f);
        a4 = fmaxf(fmaf(a4, sc[4], sh[4]), 0.f);
        a5 = fmaxf(fmaf(a5, sc[5], sh[5]), 0.f);
        a6 = fmaxf(fmaf(a6, sc[6], sh[6]), 0.f);
        a7 = fmaxf(fmaf(a7, sc[7], sh[7]), 0.f);
        out.x = rne_bf16(a0) | (rne_bf16(a1) << 16);
        out.y = rne_bf16(a2) | (rne_bf16(a3) << 16);
        out.z = rne_bf16(a4) | (rne_bf16(a5) << 16);
        out.w = rne_bf16(a6) | (rne_bf16(a7) << 16);
    } else {
        out.x = out.y = out.z = out.w = 0u;   // PyG 0-fill (pre-GEMM, no BN)
    }
    agg16[(size_t)node * 16 + lane] = out;
}

// ============================================================================
// MFMA GEMM: acc = [agg16 | xin16] @ Wt^T + bias, fused BN col-stats.
// OUT_BF16=1 -> write h as bf16 (2B stores); else fp32.
// 256 thr = 4 waves (2x2), BM=128, BN=128, per wave 64x64 (4x4 frags 16x16).
// ============================================================================
template <int OUT_BF16>
__device__ __forceinline__
void gemm_bf16_body(const unsigned short* __restrict__ agg16,
                    const unsigned short* __restrict__ xin16,
                    const unsigned short* __restrict__ Wt,
                    const float* __restrict__ bias,
                    void* __restrict__ hout, float* __restrict__ stats, int nrows) {
    __shared__ float redS[4][128];
    __shared__ float redQ[4][128];

    const int t = threadIdx.x;
    const int w = t >> 6, l = t & 63;
    const int wm = w >> 1, wn = w & 1;
    const int r16 = l & 15, g = l >> 4;
    const int blockRow = blockIdx.x * 128;
    const int colBase = wn * 64;

    f32x4 acc[4][4];
#pragma unroll
    for (int m = 0; m < 4; ++m)
#pragma unroll
        for (int n = 0; n < 4; ++n) acc[m][n] = (f32x4){0.f, 0.f, 0.f, 0.f};

    const short8v az = {0, 0, 0, 0, 0, 0, 0, 0};

#pragma unroll
    for (int kt = 0; kt < 8; ++kt) {
        const unsigned short* Asrc = (kt < 4) ? agg16 : xin16;
        const int kofs = (kt < 4) ? kt * 32 : kt * 32 - 128;

        short8v b[4];
#pragma unroll
        for (int n = 0; n < 4; ++n) {
            int col = colBase + n * 16 + r16;
            b[n] = *(const short8v*)(Wt + (size_t)col * 256 + kt * 32 + g * 8);
        }
        short8v a[4];
#pragma unroll
        for (int m = 0; m < 4; ++m) {
            int row = blockRow + wm * 64 + m * 16 + r16;
            a[m] = (row < nrows)
                 ? *(const short8v*)(Asrc + (size_t)row * 128 + kofs + g * 8)
                 : az;
        }
#pragma unroll
        for (int m = 0; m < 4; ++m)
#pragma unroll
            for (int n = 0; n < 4; ++n)
                acc[m][n] = __builtin_amdgcn_mfma_f32_16x16x32_bf16(a[m], b[n], acc[m][n], 0, 0, 0);
    }

    // ---- epilogue: bias, store h, fused BN stats ----
    for (int i = t; i < 512; i += 256) {
        ((float*)redS)[i] = 0.f;
        ((float*)redQ)[i] = 0.f;
    }
    __syncthreads();

    float bcol[4];
#pragma unroll
    for (int n = 0; n < 4; ++n) bcol[n] = bias[colBase + n * 16 + r16];

    float s4[4] = {0.f, 0.f, 0.f, 0.f};
    float q4[4] = {0.f, 0.f, 0.f, 0.f};
#pragma unroll
    for (int m = 0; m < 4; ++m) {
#pragma unroll
        for (int reg = 0; reg < 4; ++reg) {
            int row = blockRow + wm * 64 + m * 16 + g * 4 + reg;   // C/D: row=(l>>4)*4+reg
            if (row < nrows) {
#pragma unroll
                for (int n = 0; n < 4; ++n) {
                    float o = acc[m][n][reg] + bcol[n];
                    int col = colBase + n * 16 + r16;               // col=l&15
                    if (OUT_BF16)
                        ((unsigned short*)hout)[(size_t)row * 128 + col] =
                            (unsigned short)rne_bf16(o);
                    else
                        ((float*)hout)[(size_t)row * 128 + col] = o;
                    s4[n] += o;
                    q4[n] += o * o;
                }
            }
        }
    }
#pragma unroll
    for (int n = 0; n < 4; ++n) {     // reduce over the 4 k-groups (same col)
        s4[n] += __shfl_xor(s4[n], 16, 64);
        s4[n] += __shfl_xor(s4[n], 32, 64);
        q4[n] += __shfl_xor(q4[n], 16, 64);
        q4[n] += __shfl_xor(q4[n], 32, 64);
    }
    if (g == 0) {
#pragma unroll
        for (int n = 0; n < 4; ++n) {
            redS[w][colBase + n * 16 + r16] = s4[n];
            redQ[w][colBase + n * 16 + r16] = q4[n];
        }
    }
    __syncthreads();
    if (t < 128) {
        float s = redS[0][t] + redS[1][t] + redS[2][t] + redS[3][t];
        float q = redQ[0][t] + redQ[1][t] + redQ[2][t] + redQ[3][t];
        atomicAdd(&stats[t], s);
        atomicAdd(&stats[128 + t], q);
    }
}

extern "C" __global__ __launch_bounds__(256)
void gemm_bf16_out16_kernel(const unsigned short* __restrict__ agg16,
                            const unsigned short* __restrict__ xin16,
                            const unsigned short* __restrict__ Wt,
                            const float* __restrict__ bias,
                            unsigned short* __restrict__ h, float* __restrict__ stats,
                            int nrows) {
    gemm_bf16_body<1>(agg16, xin16, Wt, bias, h, stats, nrows);
}

extern "C" __global__ __launch_bounds__(256)
void gemm_bf16_out32_kernel(const unsigned short* __restrict__ agg16,
                            const unsigned short* __restrict__ xin16,
                            const unsigned short* __restrict__ Wt,
                            const float* __restrict__ bias,
                            float* __restrict__ h, float* __restrict__ stats,
                            int nrows) {
    gemm_bf16_body<0>(agg16, xin16, Wt, bias, h, stats, nrows);
}

// ============================================================================
// final BN+ReLU in place fp32 (finalize fused per block)
// ============================================================================
extern "C" __global__ __launch_bounds__(256)
void bn_relu_f32_kernel(float4* __restrict__ h, const float* __restrict__ stats,
                        const float* __restrict__ gamma, const float* __restrict__ beta,
                        float inv_n, long n4) {
    __shared__ float s_ss[256];
    {
        int t = threadIdx.x;
        if (t < 128) {
            float mu = stats[t] * inv_n;
            float var = stats[128 + t] * inv_n - mu * mu;
            float sc = gamma[t] * rsqrtf(var + EPS_BN);
            s_ss[t] = sc;
            s_ss[128 + t] = beta[t] - mu * sc;
        }
        __syncthreads();
    }
    long i = (long)blockIdx.x * blockDim.x + threadIdx.x;
    long stride = (long)gridDim.x * blockDim.x;
    for (; i < n4; i += stride) {
        int c4 = (int)(i & 31) * 4;
        float4 v = h[i];
        v.x = fmaxf(fmaf(v.x, s_ss[c4 + 0], s_ss[128 + c4 + 0]), 0.f);
        v.y = fmaxf(fmaf(v.y, s_ss[c4 + 1], s_ss[128 + c4 + 1]), 0.f);
        v.z = fmaxf(fmaf(v.z, s_ss[c4 + 2], s_ss[128 + c4 + 2]), 0.f);
        v.w = fmaxf(fmaf(v.w, s_ss[c4 + 3], s_ss[128 + c4 + 3]), 0.f);
        h[i] = v;
    }
}

// ============================================================================
// fallback path (fp32 atomic scatter-max + VALU GEMM) — only if ws too small
// ============================================================================
__device__ __forceinline__ unsigned map_f(float f) {
    unsigned u = __float_as_uint(f);
    return (u & 0x80000000u) ? ~u : (u | 0x80000000u);
}
__device__ __forceinline__ float unmap_f(unsigned m) {
    return (m & 0x80000000u) ? __uint_as_float(m & 0x7FFFFFFFu) : __uint_as_float(~m);
}

extern "C" __global__ __launch_bounds__(256)
void init_sentinel_kernel(uint4* __restrict__ agg, long n4) {
    uint4 z = {0u, 0u, 0u, 0u};
    long i = (long)blockIdx.x * blockDim.x + threadIdx.x;
    long stride = (long)gridDim.x * blockDim.x;
    for (; i < n4; i += stride) agg[i] = z;
}

extern "C" __global__ __launch_bounds__(256)
void scatter_max_kernel(const float4* __restrict__ xin, const int* __restrict__ ei,
                        unsigned* __restrict__ agg, int E) {
    int t = blockIdx.x * 256 + threadIdx.x;
    int e = t >> 5;
    if (e >= E) return;
    int f4 = t & 31;
    int src = ei[e];
    int dst = ei[E + e];
    float4 v = xin[(size_t)src * 32 + f4];
    unsigned* p = agg + (size_t)dst * 128 + (size_t)f4 * 4;
    atomicMax(p + 0, map_f(v.x));
    atomicMax(p + 1, map_f(v.y));
    atomicMax(p + 2, map_f(v.z));
    atomicMax(p + 3, map_f(v.w));
}

extern "C" __global__ __launch_bounds__(256)
void unmap_kernel(unsigned* __restrict__ agg, long n) {
    long i = (long)blockIdx.x * blockDim.x + threadIdx.x;
    long stride = (long)gridDim.x * blockDim.x;
    for (; i < n; i += stride) {
        unsigned u = agg[i];
        agg[i] = __float_as_uint(u ? unmap_f(u) : 0.0f);
    }
}

extern "C" __global__
void zero_stats_kernel(float* __restrict__ stats) {
    stats[threadIdx.x] = 0.0f;
}

extern "C" __global__ __launch_bounds__(256)
void gemm_kernel(const float* __restrict__ agg, const float* __restrict__ xin,
                 const float* __restrict__ Wl, const float* __restrict__ Wr,
                 const float* __restrict__ bias, float* __restrict__ h,
                 float* __restrict__ stats, int nrows) {
    __shared__ __align__(16) float As[64][36];
    __shared__ __align__(16) float Bs[32][136];
    __shared__ float redS[4][128];
    __shared__ float redQ[4][128];

    const int t = threadIdx.x;
    const int tx = t & 15;
    const int ty = t >> 4;
    const int tx8 = tx * 8;
    const int ty4 = ty * 4;
    const int blockRow = blockIdx.x * 64;

    float acc[4][8];
#pragma unroll
    for (int j = 0; j < 4; ++j)
#pragma unroll
        for (int c = 0; c < 8; ++c) acc[j][c] = 0.0f;

    for (int kt = 0; kt < 8; ++kt) {
        const int k0 = kt * 32;
        const bool isAgg = (kt < 4);
        const float* W = isAgg ? Wl : Wr;
        const float* Asrc = isAgg ? agg : xin;
        const int kw = isAgg ? k0 : (k0 - 128);

#pragma unroll
        for (int it = 0; it < 4; ++it) {
            int idx = t + it * 256;
            int kr = idx >> 5, cq = idx & 31;
            float4 ww = *(const float4*)&W[(size_t)(kw + kr) * 128 + cq * 4];
            *(float4*)&Bs[kr][cq * 4] = ww;
        }
#pragma unroll
        for (int it = 0; it < 2; ++it) {
            int idx = t + it * 256;
            int r = idx >> 3, kq = idx & 7;
            int row_g = blockRow + r;
            float4 a = {0.f, 0.f, 0.f, 0.f};
            if (row_g < nrows)
                a = *(const float4*)&Asrc[(size_t)row_g * 128 + kw + kq * 4];
            *(float4*)&As[r][kq * 4] = a;
        }
        __syncthreads();

#pragma unroll
        for (int kk = 0; kk < 32; ++kk) {
            float aa[4];
            aa[0] = As[ty4 + 0][kk];
            aa[1] = As[ty4 + 1][kk];
            aa[2] = As[ty4 + 2][kk];
            aa[3] = As[ty4 + 3][kk];
            float4 b0 = *(const float4*)&Bs[kk][tx8];
            float4 b1 = *(const float4*)&Bs[kk][tx8 + 4];
            float bb[8] = {b0.x, b0.y, b0.z, b0.w, b1.x, b1.y, b1.z, b1.w};
#pragma unroll
            for (int j = 0; j < 4; ++j)
#pragma unroll
                for (int c = 0; c < 8; ++c)
                    acc[j][c] = fmaf(aa[j], bb[c], acc[j][c]);
        }
        __syncthreads();
    }

    float bv[8];
#pragma unroll
    for (int c = 0; c < 8; ++c) bv[c] = bias[tx8 + c];

    float s_loc[8], q_loc[8];
#pragma unroll
    for (int c = 0; c < 8; ++c) { s_loc[c] = 0.f; q_loc[c] = 0.f; }

#pragma unroll
    for (int j = 0; j < 4; ++j) {
        int row = blockRow + ty4 + j;
        if (row < nrows) {
            float o[8];
#pragma unroll
            for (int c = 0; c < 8; ++c) {
                o[c] = acc[j][c] + bv[c];
                s_loc[c] += o[c];
                q_loc[c] += o[c] * o[c];
            }
            float4 o0 = {o[0], o[1], o[2], o[3]};
            float4 o1 = {o[4], o[5], o[6], o[7]};
            *(float4*)&h[(size_t)row * 128 + tx8] = o0;
            *(float4*)&h[(size_t)row * 128 + tx8 + 4] = o1;
        }
    }

#pragma unroll
    for (int c = 0; c < 8; ++c) {
        s_loc[c] += __shfl_xor(s_loc[c], 16, 64);
        s_loc[c] += __shfl_xor(s_loc[c], 32, 64);
        q_loc[c] += __shfl_xor(q_loc[c], 16, 64);
        q_loc[c] += __shfl_xor(q_loc[c], 32, 64);
    }
    int wave = t >> 6;
    if ((t & 63) < 16) {
#pragma unroll
        for (int c = 0; c < 8; ++c) {
            redS[wave][tx8 + c] = s_loc[c];
            redQ[wave][tx8 + c] = q_loc[c];
        }
    }
    __syncthreads();
    if (t < 128) {
        float s = redS[0][t] + redS[1][t] + redS[2][t] + redS[3][t];
        float q = redQ[0][t] + redQ[1][t] + redQ[2][t] + redQ[3][t];
        atomicAdd(&stats[t], s);
        atomicAdd(&stats[128 + t], q);
    }
}

static void run_layer_atomic(const float* in_feat, const int* ei, int Nn, int Ee,
                             const float* Wl, const float* bl, const float* Wr,
                             const float* gamma, const float* beta,
                             float* agg, float* stats, float* out, hipStream_t stream) {
    long aggN = (long)Nn * 128;
    long n4 = aggN / 4;

    zero_stats_kernel<<<1, 256, 0, stream>>>(stats);
    int initBlocks = (int)((n4 + 255) / 256);
    if (initBlocks > 4096) initBlocks = 4096;
    init_sentinel_kernel<<<initBlocks, 256, 0, stream>>>((uint4*)agg, n4);
    int sb = (int)(((long)Ee * 32 + 255) / 256);
    scatter_max_kernel<<<sb, 256, 0, stream>>>((const float4*)in_feat, ei,
                                               (unsigned*)agg, Ee);
    int ub = (int)((aggN + 255) / 256);
    if (ub > 8192) ub = 8192;
    unmap_kernel<<<ub, 256, 0, stream>>>((unsigned*)agg, aggN);
    gemm_kernel<<<(Nn + 63) / 64, 256, 0, stream>>>(agg, in_feat, Wl, Wr, bl,
                                                    out, stats, Nn);
    int bnBlocks = (int)((n4 + 255) / 256);
    if (bnBlocks > 8192) bnBlocks = 8192;
    bn_relu_f32_kernel<<<bnBlocks, 256, 0, stream>>>((float4*)out, stats, gamma, beta,
                                                     1.0f / (float)Nn, n4);
}

// ============================================================================
// host-side orchestration
// ============================================================================
extern "C" void kernel_launch(void* const* d_in, const int* in_sizes, int n_in,
                              void* d_out, int out_size, void* d_ws, size_t ws_size,
                              hipStream_t stream) {
    (void)n_in; (void)out_size;
    const float* x     = (const float*)d_in[0];
    const int*   ei    = (const int*)d_in[1];
    const float* W0_l  = (const float*)d_in[2];
    const float* b0_l  = (const float*)d_in[3];
    const float* W0_r  = (const float*)d_in[4];
    const float* g0    = (const float*)d_in[5];
    const float* be0   = (const float*)d_in[6];
    const float* W1_l  = (const float*)d_in[7];
    const float* b1_l  = (const float*)d_in[8];
    const float* W1_r  = (const float*)d_in[9];
    const float* g1    = (const float*)d_in[10];
    const float* be1   = (const float*)d_in[11];

    int Nn = in_sizes[0] / 128;
    int Ee = in_sizes[1] / 2;
    long n4 = (long)Nn * 32;                   // float4 / uint2 row-elems
    float inv_n = 1.0f / (float)Nn;

    char* p = (char*)d_ws;
    unsigned short* xy16 = (unsigned short*)p;  p += (size_t)Nn * 128 * 2;  // x16, later y16
    unsigned short* agg16 = (unsigned short*)p; p += (size_t)Nn * 128 * 2;
    float* stats0 = (float*)p;                  p += 256 * sizeof(float);
    float* stats1 = (float*)p;                  p += 256 * sizeof(float);
    unsigned short* Wt0 = (unsigned short*)p;   p += 128 * 256 * 2;
    unsigned short* Wt1 = (unsigned short*)p;   p += 128 * 256 * 2;
    int* head = (int*)p;                        p += (size_t)Nn * sizeof(int);
    uint2* pair = (uint2*)p;                    p += (size_t)Ee * sizeof(uint2);
    size_t needed = (size_t)(p - (char*)d_ws);
    float* out = (float*)d_out;
    unsigned short* h1 = (unsigned short*)d_out;   // h1-bf16 parked in d_out (dead by gemm2)

    if (ws_size >= needed) {
        // ---- bf16 MFMA path ----
        int cvB = (int)((n4 + 255) / 256);
        if (cvB > 4096) cvB = 4096;
        int hB = (Nn + 255) / 256;
        prep_kernel<<<cvB + 256 + hB, 256, 0, stream>>>(
            (const float4*)x, (uint2*)xy16, n4, cvB,
            W0_l, W0_r, Wt0, W1_l, W1_r, Wt1, head, Nn);
        link_kernel<<<(Ee + 255) / 256, 256, 0, stream>>>(ei, head, pair, Ee);

        int gB = (Nn * 16 + 255) / 256;
        int mB = (Nn + 127) / 128;
        int bnB = (int)((n4 + 255) / 256);
        if (bnB > 8192) bnB = 8192;

        // layer 1: agg1 <- max x16; h1(bf16) -> d_out; stats0
        gather_max_ll16_kernel<<<gB, 256, 0, stream>>>(
            (const uint4*)xy16, head, pair, (uint4*)agg16, stats0, Nn);
        gemm_bf16_out16_kernel<<<mB, 256, 0, stream>>>(agg16, xy16, Wt0, b0_l,
                                                       h1, stats0, Nn);
        // layer 2: agg2 = relu(bn0(max h1)), y1 = relu(bn0(h1)) -> xy16; stats1 zeroed
        gather_max_bn_kernel<<<gB, 256, 0, stream>>>(
            (const uint4*)h1, head, pair, stats0, g0, be0, inv_n,
            (uint4*)agg16, (uint4*)xy16, stats1, Nn);
        gemm_bf16_out32_kernel<<<mB, 256, 0, stream>>>(agg16, xy16, Wt1, b1_l,
                                                       out, stats1, Nn);
        bn_relu_f32_kernel<<<bnB, 256, 0, stream>>>((float4*)out, stats1, g1, be1,
                                                    inv_n, n4);
    } else {
        // ---- fallback: fp32 atomic path ----
        float* agg = (float*)d_ws;
        float* fstats = (float*)((char*)d_ws + (size_t)Nn * 128 * sizeof(float));
        run_layer_atomic(x, ei, Nn, Ee, W0_l, b0_l, W0_r, g0, be0,
                         agg, fstats, out, stream);
        run_layer_atomic(out, ei, Nn, Ee, W1_l, b1_l, W1_r, g1, be1,
                         agg, fstats, out, stream);
    }
}